// Round 1
// 378.401 us; speedup vs baseline: 1.2963x; 1.2963x over previous
//
#include <hip/hip_runtime.h>
#include <hip/hip_bf16.h>
#include <math.h>

// ---------------------------------------------------------------------------
// JointWiseFeedForward: T=16 independent per-position FFNs.
//   x:[16384,2048] f32 -> reshape [16384,128,16]; h = einsum(bct,oct)->bot with
//   w1:[512,128,16]; gelu(exact erf; we use tanh-form, |err|<1e-3);
//   y = einsum with w2:[128,512,16]; out feature = o*16+t.
// Strategy: bf16 MFMA (threshold is bf16-tolerant), 4 kernels:
//   k_packw: w1/w2 fp32 -> bf16 in MFMA-fragment order (per-lane b128 streams)
//   k_xt:    x -> xt[t][row][c] bf16 (LDS transpose, coalesced both sides)
//   k_ffn:   fused GEMM1(swapped)->gelu->bpermute lane transform->GEMM2
//            yt written bf16 IN-PLACE over xt (block-exclusive slabs)
//   k_out:   yt -> out fp32 (LDS transpose)
// R4 (this round): k_ffn was latency-bound (MfmaUtil 12%, VALUBusy 25%,
//   occupancy 22.6% — reg-capped at 2 waves/SIMD by the 128 accums).
//   Fixes:
//   1. x fragments hoisted to 32 VGPRs (loaded once from xt, reused by all
//      K-chunks) — xs LDS staging + barrier eliminated.
//   2. Weights streamed via __builtin_amdgcn_global_load_lds (16B) into a
//      2x32KB LDS double buffer, 2-phase pipeline (stage(next) issued before
//      compute(cur), one vmcnt-drain barrier per half-chunk). Weights shared
//      by all 4 waves: L2 weight traffic 2GB -> 512MB, latency hidden under
//      the MFMA+gelu phase. Half-chunks of 64 cff (acc1 drops 64->32 regs).
//   3. All f32->bf16 packing via v_cvt_pk_bf16_f32 (1 instr vs ~9 manual RNE).
// ---------------------------------------------------------------------------

typedef __attribute__((ext_vector_type(8))) short bf16x8;
typedef __attribute__((ext_vector_type(4))) float f32x4;

#define MFMA16(a,b,c) __builtin_amdgcn_mfma_f32_16x16x32_bf16((a),(b),(c),0,0,0)

#define N_ROWS   16384
#define XT_PLANE (16384*128)     // elems per t-plane in xt/yt
#define W_TSTR   65536           // packed-weight elems per t  (4*8*4*64*8)
#define W_JSTR   16384           // packed-weight elems per jc chunk (8*4*64*8)

static __device__ __forceinline__ unsigned short f2bf(float f){
  union{float f; unsigned u;} v; v.f = f;
  return (unsigned short)((v.u + 0x7FFFu + ((v.u>>16)&1u))>>16);   // RNE
}
// packed RNE f32x2 -> bf16x2 via HW instruction (D.lo=cvt(lo), D.hi=cvt(hi))
static __device__ __forceinline__ unsigned cvtpk(float lo, float hi){
  unsigned r;
  asm("v_cvt_pk_bf16_f32 %0, %1, %2" : "=v"(r) : "v"(lo), "v"(hi));
  return r;
}
// gelu(x) = x * sigmoid(1.5957691x + 0.0713548x^3)  (tanh form)
static __device__ __forceinline__ float gelu_fast(float x){
  float x2 = x*x;
  float m  = x*(-1.5957691216f - 0.0713548163f*x2);
  float e  = __expf(m);
  return x*__builtin_amdgcn_rcpf(1.0f + e);
}

typedef __attribute__((address_space(1))) const unsigned int gas_u32;
typedef __attribute__((address_space(3))) unsigned int las_u32;
static __device__ __forceinline__ void gload16(const void* g, void* l){
  __builtin_amdgcn_global_load_lds((gas_u32*)g, (las_u32*)l, 16, 0, 0);
}

// ---------------- weight pack ------------------------------------------------
// w1p[t][jc][mt][ks][lane][j] : A-frag for GEMM1-swapped: lane(q=l>>4,i=l&15)
//   holds A[m=cff=jc*128+mt*16+i][k=cin=ks*32+q*8+j]  = w1[o][c][t]
// w2p[t][jc][nt2][ks2][lane][j]: B-frag for GEMM2: lane holds
//   B[k=cff=jc*128+ks2*32+q*8+j][n=cout=nt2*16+i]     = w2[o2][cf][t]
__global__ __launch_bounds__(256) void k_packw(const float* __restrict__ w1,
                                               const float* __restrict__ w2,
                                               unsigned short* __restrict__ w1p,
                                               unsigned short* __restrict__ w2p){
  int g = blockIdx.x*256 + threadIdx.x;           // 0..262143
  bool is1 = (g < 131072);
  int gg = is1 ? g : (g - 131072);
  int l  = gg & 63, q = (l>>4), i = l & 15;
  int ks = (gg>>6)&3, m8 = (gg>>8)&7, jc = (gg>>11)&3, t = (gg>>13)&15;
  union { unsigned short s[8]; bf16x8 v; } u;
  if (is1){
    int o  = jc*128 + m8*16 + i;
    int c0 = ks*32 + q*8;
    #pragma unroll
    for (int j=0;j<8;++j) u.s[j] = f2bf(w1[(o*128 + c0 + j)*16 + t]);
    *(bf16x8*)(w1p + (size_t)gg*8) = u.v;
  } else {
    int o2  = m8*16 + i;
    int cf0 = jc*128 + ks*32 + q*8;
    #pragma unroll
    for (int j=0;j<8;++j) u.s[j] = f2bf(w2[(o2*512 + cf0 + j)*16 + t]);
    *(bf16x8*)(w2p + (size_t)gg*8) = u.v;
  }
}

// ---------------- x transpose: x[r][c*16+t] -> xt[t][r][c] (bf16) -----------
__global__ __launch_bounds__(256) void k_xt(const float* __restrict__ x,
                                            unsigned short* __restrict__ xt){
  __shared__ unsigned short ls[8*16*136];         // [r][t][c], c-stride 136
  const int r0 = blockIdx.x*8;
  const int tid = threadIdx.x;
  #pragma unroll
  for (int it=0; it<16; ++it){
    int f4  = it*256 + tid;                       // float4 index in 8x2048 slab
    int row = f4>>9, rem = f4&511;
    int c = rem>>2, t0 = (rem&3)*4;               // f=rem*4: c=f>>4, t=f&15
    float4 v = *(const float4*)(x + (size_t)(r0+row)*2048 + rem*4);
    ls[(row*16 + t0+0)*136 + c] = f2bf(v.x);
    ls[(row*16 + t0+1)*136 + c] = f2bf(v.y);
    ls[(row*16 + t0+2)*136 + c] = f2bf(v.z);
    ls[(row*16 + t0+3)*136 + c] = f2bf(v.w);
  }
  __syncthreads();
  const int t = tid>>4, cg = tid&15;
  #pragma unroll
  for (int r=0;r<8;++r){
    bf16x8 v = *(const bf16x8*)(ls + (r*16 + t)*136 + cg*8);
    *(bf16x8*)(xt + (size_t)t*XT_PLANE + (size_t)(r0+r)*128 + cg*8) = v;
  }
}

// ---------------- fused FFN GEMM --------------------------------------------
// block = (row-tile of 128, token t); 4 waves x 32 rows.
// GEMM1 swapped: D1[m=cff][n=row] = W1 (A, LDS b128) * x (B, registers).
// C-frag: lane(q,i): row=i(+16*nt), cff(local in 64-half)=mt*16+4q+reg
// -> gelu -> v_cvt_pk_bf16_f32 -> ds_bpermute into GEMM2 A-frag (in-wave).
// GEMM2: Y[m=row][n=cout] += H * W2 (B, LDS b128); Y in 64 VGPRs.
// Weights: per half-chunk (64 cff) 16KB w1 + 16KB w2 staged cooperatively by
// all 4 waves via global_load_lds into ws[cur^1] while ws[cur] is computed;
// one __syncthreads (vmcnt drain) per half-chunk. 8 half-chunks total.
__global__ __launch_bounds__(256,2) void k_ffn(const unsigned short* __restrict__ xt,
                                               const unsigned short* __restrict__ w1p,
                                               const unsigned short* __restrict__ w2p,
                                               unsigned short* __restrict__ yt){
  __shared__ unsigned short ws[2*16384];          // 2 x (16KB w1-half + 16KB w2-half)
  const int bx = blockIdx.x;
  const int t = bx>>7, rt = bx&127, r0 = rt<<7;
  const int tid = threadIdx.x;
  const int wv = tid>>6, l = tid&63, q = l>>4, i = l&15;

  const unsigned short* w1t = w1p + (size_t)t*W_TSTR;
  const unsigned short* w2t = w2p + (size_t)t*W_TSTR;

  // stage half-chunk hc (jc=hc>>1, half=hc&1) into buffer buf.
  // 32 chunks of 1KB (one chunk = one 64-lane b128 frag): waves 0,1 -> w1
  // (global-contiguous 16KB), waves 2,3 -> w2 (strided frags).
  auto stage = [&](int hc, int buf){
    const int jc = hc>>1, half = hc&1;
    const unsigned short* w1c = w1t + jc*W_JSTR + half*8192;
    const unsigned short* w2c = w2t + jc*W_JSTR + half*1024;
    unsigned short* Wb = ws + buf*16384;
    #pragma unroll
    for (int c=0;c<8;++c){
      int k = wv*8 + c;                           // wave-uniform
      if (k < 16){
        gload16(w1c + k*512 + l*8, Wb + k*512 + l*8);
      } else {
        int f = k - 16;                           // f = nt2*2 + ks2'
        gload16(w2c + (f>>1)*2048 + (f&1)*512 + l*8, Wb + 8192 + f*512 + l*8);
      }
    }
  };

  stage(0, 0);

  // x fragments: xb[ks][nt] = x[row=r0+wv*32+nt*16+i][cin=ks*32+q*8 ..+7],
  // loaded once from xt (64B-granule coalesced), reused by all 8 half-chunks.
  bf16x8 xb[4][2];
  {
    const unsigned short* xp = xt + (size_t)t*XT_PLANE + (size_t)(r0 + wv*32)*128;
    #pragma unroll
    for (int ks=0; ks<4; ++ks){
      xb[ks][0] = *(const bf16x8*)(xp + (size_t)i*128 + ks*32 + q*8);
      xb[ks][1] = *(const bf16x8*)(xp + (size_t)(i+16)*128 + ks*32 + q*8);
    }
  }
  __syncthreads();                                // stage(0) landed

  f32x4 accY[2][8];
  #pragma unroll
  for (int a=0;a<2;++a)
    #pragma unroll
    for (int b=0;b<8;++b) accY[a][b] = (f32x4){0.f,0.f,0.f,0.f};

  const int idxA = ((q&1)*32 + i)*4;              // src lane*4 for frag j0..3
  const int idxB = idxA + 64;                     // +16 lanes for frag j4..7
  const int lo32 = (l < 32);                      // q>>1 == 0 ?

  int cur = 0;
  #pragma unroll 1
  for (int hc=0; hc<8; ++hc){                     // 8 half-chunks of 64 cff
    if (hc < 7) stage(hc+1, cur^1);               // issue loads BEFORE compute

    const unsigned short* W1 = ws + cur*16384;
    const unsigned short* W2 = W1 + 8192;

    // GEMM1 half: D1[cff 64][row 32] ; acc1[mt][nt]
    f32x4 acc1[4][2];
    #pragma unroll
    for (int a=0;a<4;++a){ acc1[a][0]=(f32x4){0,0,0,0}; acc1[a][1]=(f32x4){0,0,0,0}; }
    #pragma unroll
    for (int ks=0; ks<4; ++ks){                   // K = cin = 128
      #pragma unroll
      for (int mt=0; mt<4; ++mt){
        bf16x8 af = *(const bf16x8*)(W1 + (mt*4+ks)*512 + l*8);
        acc1[mt][0] = MFMA16(af, xb[ks][0], acc1[mt][0]);
        acc1[mt][1] = MFMA16(af, xb[ks][1], acc1[mt][1]);
      }
    }

    // gelu + HW pack: (reg0,1)->pk[..][0], (reg2,3)->pk[..][1]
    unsigned pk[4][2][2];
    #pragma unroll
    for (int mt=0; mt<4; ++mt)
      #pragma unroll
      for (int nt=0; nt<2; ++nt){
        f32x4 v = acc1[mt][nt];
        pk[mt][nt][0] = cvtpk(gelu_fast(v.x), gelu_fast(v.y));
        pk[mt][nt][1] = cvtpk(gelu_fast(v.z), gelu_fast(v.w));
      }

    // GEMM2 half: K = 64 local cff; ks2' = 0..1
    #pragma unroll
    for (int ks2=0; ks2<2; ++ks2){
      bf16x8 a2[2];
      #pragma unroll
      for (int nt=0; nt<2; ++nt){
        // target lane (q,i) needs H[row=nt*16+i][cff_local=ks2*32+8q+j];
        // source: acc tile mt=2*ks2+(q>>1), src lane (2(q&1)+(jj>>1))*16+i.
        int pA0=(int)pk[2*ks2  ][nt][0], pA1=(int)pk[2*ks2  ][nt][1];
        int pB0=(int)pk[2*ks2+1][nt][0], pB1=(int)pk[2*ks2+1][nt][1];
        int a0 = __builtin_amdgcn_ds_bpermute(idxA, pA0);
        int b0 = __builtin_amdgcn_ds_bpermute(idxA, pB0);
        int a1 = __builtin_amdgcn_ds_bpermute(idxA, pA1);
        int b1 = __builtin_amdgcn_ds_bpermute(idxA, pB1);
        int a2r= __builtin_amdgcn_ds_bpermute(idxB, pA0);
        int b2 = __builtin_amdgcn_ds_bpermute(idxB, pB0);
        int a3 = __builtin_amdgcn_ds_bpermute(idxB, pA1);
        int b3 = __builtin_amdgcn_ds_bpermute(idxB, pB1);
        union{ int ii[4]; bf16x8 v; } u;
        u.ii[0] = lo32 ? a0 : b0;
        u.ii[1] = lo32 ? a1 : b1;
        u.ii[2] = lo32 ? a2r: b2;
        u.ii[3] = lo32 ? a3 : b3;
        a2[nt] = u.v;
      }
      #pragma unroll
      for (int nt2=0; nt2<8; ++nt2){
        bf16x8 bf = *(const bf16x8*)(W2 + (nt2*2+ks2)*512 + l*8);
        accY[0][nt2] = MFMA16(a2[0], bf, accY[0][nt2]);
        accY[1][nt2] = MFMA16(a2[1], bf, accY[1][nt2]);
      }
    }

    __syncthreads();        // drain stage loads (vmcnt0) + release ws[cur]
    cur ^= 1;
  }

  // epilogue: Y[m=row=wv*32+mt2*16+4q+reg][n=o=nt2*16+i] -> yt bf16 (in-place)
  unsigned short* yp = yt + (size_t)t*XT_PLANE + (size_t)(r0 + wv*32)*128;
  #pragma unroll
  for (int mt2=0; mt2<2; ++mt2)
    #pragma unroll
    for (int nt2=0; nt2<8; ++nt2){
      f32x4 v = accY[mt2][nt2];
      unsigned p01 = cvtpk(v.x, v.y);
      unsigned p23 = cvtpk(v.z, v.w);
      int o = nt2*16 + i;
      int rowb = mt2*16 + q*4;
      yp[(rowb+0)*128 + o] = (unsigned short)(p01 & 0xffffu);
      yp[(rowb+1)*128 + o] = (unsigned short)(p01 >> 16);
      yp[(rowb+2)*128 + o] = (unsigned short)(p23 & 0xffffu);
      yp[(rowb+3)*128 + o] = (unsigned short)(p23 >> 16);
    }
}

// ---------------- output transpose: yt[t][r][o] -> out[r][o*16+t] fp32 ------
__global__ __launch_bounds__(256) void k_out(const unsigned short* __restrict__ yt,
                                             float* __restrict__ out){
  __shared__ float ls[4*2176];                    // [r][o][t], o-stride 17
  const int r0 = blockIdx.x*4;
  const int tid = threadIdx.x;
  const int t = tid>>4, og = tid&15;
  #pragma unroll
  for (int r=0;r<4;++r){
    bf16x8 v = *(const bf16x8*)(yt + (size_t)t*XT_PLANE + (size_t)(r0+r)*128 + og*8);
    #pragma unroll
    for (int j=0;j<8;++j){
      union{unsigned u; float f;} c; c.u = ((unsigned)(unsigned short)v[j])<<16;
      ls[r*2176 + (og*8+j)*17 + t] = c.f;
    }
  }
  __syncthreads();
  #pragma unroll
  for (int r=0;r<4;++r)
    #pragma unroll
    for (int it=0; it<2; ++it){
      int f4 = it*256 + tid; int o = f4>>2; int t0 = (f4&3)*4;
      const float* p = ls + r*2176 + o*17 + t0;
      float4 v; v.x=p[0]; v.y=p[1]; v.z=p[2]; v.w=p[3];
      *(float4*)(out + (size_t)(r0+r)*2048 + (size_t)f4*4) = v;
    }
}

// ---------------- exact fp32 fallback (if ws too small) ---------------------
__global__ __launch_bounds__(128) void k_naive(const float* __restrict__ x,
                                               const float* __restrict__ w1,
                                               const float* __restrict__ w2,
                                               float* __restrict__ out){
  int bid = blockIdx.x; int t = bid & 15; int row = bid >> 4;
  int tid = threadIdx.x;
  __shared__ float xsm[128]; __shared__ float hsm[512];
  xsm[tid] = x[(size_t)row*2048 + tid*16 + t];
  __syncthreads();
  for (int kk=0; kk<4; ++kk){
    int o = kk*128 + tid; float a = 0.f;
    for (int c=0;c<128;++c) a += xsm[c]*w1[(o*128+c)*16+t];
    hsm[o] = 0.5f*a*(1.0f+erff(a*0.70710678f));
  }
  __syncthreads();
  float a = 0.f;
  for (int cf=0; cf<512; ++cf) a += hsm[cf]*w2[(tid*512+cf)*16+t];
  out[(size_t)row*2048 + tid*16 + t] = a;
}

// ---------------------------------------------------------------------------
extern "C" void kernel_launch(void* const* d_in, const int* in_sizes, int n_in,
                              void* d_out, int out_size, void* d_ws, size_t ws_size,
                              hipStream_t stream){
  const float* x  = (const float*)d_in[0];
  const float* w1 = (const float*)d_in[1];
  const float* w2 = (const float*)d_in[2];
  float* out = (float*)d_out;

  const size_t NEEDED = 71303168ULL; // 67 MB xt/yt + 2+2 MB packed weights
  if (ws_size < NEEDED || d_ws == nullptr){
    k_naive<<<dim3(16384*16), dim3(128), 0, stream>>>(x, w1, w2, out);
    return;
  }
  unsigned short* xt  = (unsigned short*)d_ws;    // doubles as yt (in-place)
  unsigned short* w1p = xt + 33554432;
  unsigned short* w2p = w1p + 1048576;

  k_packw<<<dim3(1024), dim3(256), 0, stream>>>(w1, w2, w1p, w2p);
  k_xt  <<<dim3(2048), dim3(256), 0, stream>>>(x, xt);
  k_ffn <<<dim3(2048), dim3(256), 0, stream>>>(xt, w1p, w2p, xt);
  k_out <<<dim3(4096), dim3(256), 0, stream>>>(xt, out);
}